// Round 13
// baseline (68.827 us; speedup 1.0000x reference)
//
#include <hip/hip_runtime.h>
#include <hip/hip_bf16.h>
#include <math.h>

#define D_MODEL 1024
#define LSEQ 2048
#define BATCH 2
#define NROWS (BATCH*LSEQ)   // 4096
#define NACT 16              // active decay chunks
#define CHSL 16              // decay chunk length

typedef __bf16 bf16;
typedef __attribute__((ext_vector_type(8))) __bf16 bf16x8;
typedef __attribute__((ext_vector_type(4))) __bf16 bf16x4;
typedef __attribute__((ext_vector_type(4))) float f32x4;

__device__ __forceinline__ float sigA(float ap) {
    return fmaxf(1.0f / (1.0f + expf(-ap)), 1e-30f);
}

// async global->LDS, 16B/lane; LDS dest = wave-uniform base + lane*16
__device__ __forceinline__ void gload_lds16(const void* g, void* l) {
    __builtin_amdgcn_global_load_lds(
        (const __attribute__((address_space(1))) void*)g,
        (__attribute__((address_space(3))) void*)l, 16, 0, 0);
}

// LLC-direct (sc1) stores: device-visible without cache maintenance.
__device__ __forceinline__ void store_f32_llc(float* p, float v) {
    __hip_atomic_store(p, v, __ATOMIC_RELAXED, __HIP_MEMORY_SCOPE_AGENT);
}
__device__ __forceinline__ void store_u64_llc(void* p, bf16x4 v) {
    union { bf16x4 h; unsigned long long u; } cv; cv.h = v;
    __hip_atomic_store((unsigned long long*)p, cv.u, __ATOMIC_RELAXED, __HIP_MEMORY_SCOPE_AGENT);
}

// Dataflow sync primitives (no grid barrier):
// producer: sc1 data stores -> vmcnt(0) -> syncthreads -> one device-scope atomicAdd
__device__ __forceinline__ void signal_done(unsigned* p) {
    asm volatile("s_waitcnt vmcnt(0) lgkmcnt(0)" ::: "memory");
    __syncthreads();
    if (threadIdx.x == 0) atomicAdd(p, 1u);
}
// consumer: tid0 spins on the single counter it needs, then block proceeds
__device__ __forceinline__ void wait_ge(unsigned* p, unsigned target) {
    if (threadIdx.x == 0)
        while (__hip_atomic_load(p, __ATOMIC_RELAXED, __HIP_MEMORY_SCOPE_AGENT) < target)
            __builtin_amdgcn_s_sleep(2);
    __syncthreads();
    asm volatile("" ::: "memory");
}

// One persistent kernel, 512 blocks x 256 threads (2/CU: 72KB LDS + launch_bounds).
// Dataflow: {decay|wcast} -> prep -> GEMM -> LN, each block waiting only on ITS producers.
// counters: sync[0..1]=pdone(batch,->64), sync[2]=wdone(->384),
//           sync[16..79]=gdone(mtile,->8), sync[80..143]=zdone(mtile,->8)
__global__ void __launch_bounds__(256, 2) k_fused(const float* __restrict__ W,
                                                  bf16* __restrict__ Wb,
                                                  const float* __restrict__ x,
                                                  const float* __restrict__ A_param,
                                                  const float* __restrict__ Bv,
                                                  const float* __restrict__ Cv,
                                                  const float* __restrict__ Dv,
                                                  float* __restrict__ partial,
                                                  bf16* __restrict__ G,
                                                  bf16* __restrict__ Z,
                                                  const float* __restrict__ bias,
                                                  const float* __restrict__ gamma,
                                                  const float* __restrict__ beta,
                                                  float* __restrict__ out,
                                                  unsigned* __restrict__ sync) {
    __shared__ __align__(16) bf16 S[3 * 12288];   // 72KB (GEMM phase)
    const int bid = blockIdx.x;
    const int tid = threadIdx.x;
    unsigned* pdone = sync;
    unsigned* wdone = sync + 2;
    unsigned* gdone = sync + 16;
    unsigned* zdone = sync + 80;

    // ---------------- Role work: decay partials (blocks 0..127) | W cast (blocks 128..511)
    if (bid < 128) {
        const int c = bid & 15, dg = (bid >> 4) & 3, b = bid >> 6;
        const int d = dg * 256 + tid;
        const float A = sigA(A_param[d]);
        const float l2A = log2f(A);
        const int s0 = c * CHSL;
        float w = exp2f((float)s0 * l2A);
        float sum = 0.0f;
        const int jmax = (c == NACT - 1) ? (LSEQ - s0) : CHSL;
        if (w != 0.0f) {
            const float* xp = x + ((size_t)b * LSEQ + s0) * D_MODEL + d;
            for (int j0 = 0; j0 < jmax; j0 += 8) {
                if (w == 0.0f) break;
                #pragma unroll
                for (int j = 0; j < 8; ++j) {
                    sum += w * xp[(size_t)(j0 + j) * D_MODEL];
                    w *= A;
                }
            }
        }
        store_f32_llc(&partial[((size_t)b * NACT + c) * D_MODEL + d], sum);
        signal_done(&pdone[b]);
    } else {
        for (int i = (bid - 128) * 256 + tid; i < 262144; i += 384 * 256) {
            const int idx = i * 4;
            f32x4 v = *reinterpret_cast<const f32x4*>(W + idx);
            bf16x4 o;
            #pragma unroll
            for (int k = 0; k < 4; ++k) o[k] = (bf16)v[k];
            store_u64_llc(Wb + idx, o);
        }
        signal_done(wdone);
    }

    // ---------------- Prep: conv closed-form + skip + exact GELU -> bf16 G (8 rows/block)
    {
        const int r0 = (bid & 7) * 512 + (bid >> 3) * 8;
        const int b = r0 >> 11;
        wait_ge(&pdone[b], 64);                    // all decay partials of my batch
        const int i0 = r0 & 2047;
        const int d0 = tid * 4;
        f32x4 P = {0.f, 0.f, 0.f, 0.f};
        #pragma unroll
        for (int c = 0; c < NACT; ++c)
            P += *reinterpret_cast<const f32x4*>(partial + ((size_t)b * NACT + c) * D_MODEL + d0);
        float A4[4], coeff[4], dvv[4], w[4];
        #pragma unroll
        for (int k = 0; k < 4; ++k) {
            A4[k] = sigA(A_param[d0 + k]);
            float l2 = log2f(A4[k]);
            coeff[k] = Cv[d0 + k] * Bv[d0 + k] * P[k];
            dvv[k] = Dv[d0 + k];
            w[k] = exp2f((float)(LSEQ - 1 - (i0 + 7)) * l2);   // conv(i) = coeff * A^(L-1-i)
        }
        #pragma unroll
        for (int j = 7; j >= 0; --j) {
            const int i = i0 + j;
            f32x4 xv = *reinterpret_cast<const f32x4*>(x + ((size_t)b * LSEQ + i) * D_MODEL + d0);
            bf16x4 g;
            #pragma unroll
            for (int k = 0; k < 4; ++k) {
                float u = coeff[k] * w[k] + dvv[k] * xv[k];
                g[k] = (bf16)(0.5f * u * (1.0f + erff(u * 0.70710678118654752f)));
                w[k] *= A4[k];
            }
            store_u64_llc(G + ((size_t)b * LSEQ + i) * D_MODEL + d0, g);
        }
        signal_done(&gdone[r0 >> 6]);              // my 8 rows' m-tile
    }

    // ---------------- GEMM: Z = bf16(G @ Wb^T + bias)  [R7 pipeline, swapped-operand epilogue]
    {
        const int lane = tid & 63, wave = tid >> 6;
        const int bx = (bid & 7) * 8 + ((bid >> 3) & 7);   // m-tile
        const int by = bid >> 6;                           // n-tile
        const int row0 = bx * 64, col0 = by * 128;
        const int wr = wave >> 1, wc = wave & 1;           // wave tile 32x64
        const int fr = lane & 15, q = lane >> 4;
        const int fx = fr & 7;
        f32x4 acc[2][4] = {};

        wait_ge(wdone, 384);                       // Wb complete
        wait_ge(&gdone[bx], 8);                    // my A-panel rows complete

        const int lr8 = lane >> 3;
        const int sb = 16 * ((lane & 7) ^ lr8);    // swizzled source byte-in-row
        const bf16* srcbase[6];
        #pragma unroll
        for (int r = 0; r < 6; ++r) {
            const int c = wave * 6 + r;
            const bf16* mat;
            int row;
            if (c < 8) { mat = G;  row = row0 + c * 8 + lr8; }
            else       { mat = Wb; row = col0 + (c - 8) * 8 + lr8; }
            srcbase[r] = (const bf16*)((const char*)(mat + (size_t)row * D_MODEL) + sb);
        }

        auto stage = [&](int buf, int k0) {
            #pragma unroll
            for (int r = 0; r < 6; ++r)
                gload_lds16(srcbase[r] + k0, &S[buf * 12288 + (wave * 6 + r) * 512]);
        };

        bf16x8 aE[2][2], bE[4][2], aO[2][2], bO[4][2];

        auto readFrags = [&](int bufI, bf16x8 (&a)[2][2], bf16x8 (&bb)[4][2]) {
            const bf16* SA = &S[bufI * 12288];
            const bf16* SB = SA + 4096;
            #pragma unroll
            for (int fm = 0; fm < 2; ++fm)
                #pragma unroll
                for (int ks = 0; ks < 2; ++ks)
                    a[fm][ks] = *reinterpret_cast<const bf16x8*>(
                        SA + (wr * 32 + fm * 16 + fr) * 64 + 8 * ((4 * ks + q) ^ fx));
            #pragma unroll
            for (int fn = 0; fn < 4; ++fn)
                #pragma unroll
                for (int ks = 0; ks < 2; ++ks)
                    bb[fn][ks] = *reinterpret_cast<const bf16x8*>(
                        SB + (wc * 64 + fn * 16 + fr) * 64 + 8 * ((4 * ks + q) ^ fx));
        };

        // SWAPPED operands: D[i][j] = sum_k Wb[colbase+i][k] * G[rowbase+j][k]
        // -> lane holds one G-row (j=lane&15) and 4 consecutive cols (i=(lane>>4)*4+r)
        auto mfmaAll = [&](bf16x8 (&a)[2][2], bf16x8 (&bb)[4][2]) {
            __builtin_amdgcn_s_setprio(1);
            #pragma unroll
            for (int fm = 0; fm < 2; ++fm)
                #pragma unroll
                for (int fn = 0; fn < 4; ++fn)
                    #pragma unroll
                    for (int ks = 0; ks < 2; ++ks)
                        acc[fm][fn] = __builtin_amdgcn_mfma_f32_16x16x32_bf16(bb[fn][ks], a[fm][ks], acc[fm][fn], 0, 0, 0);
            __builtin_amdgcn_s_setprio(0);
        };

        stage(0, 0);
        stage(1, 64);
        asm volatile("s_waitcnt vmcnt(6)" ::: "memory");   // tile0 landed (tile1 in flight)
        __builtin_amdgcn_s_barrier();
        __builtin_amdgcn_sched_barrier(0);
        readFrags(0, aE, bE);

        #define ITER_BODY(T, ACUR, BCUR, ANXT, BNXT)                                   \
        {                                                                              \
            if ((T) + 2 < 16) stage(((T) + 2) % 3, ((T) + 2) * 64);                    \
            __builtin_amdgcn_sched_barrier(0);                                         \
            asm volatile("s_waitcnt lgkmcnt(0)" ::: "memory");                         \
            if ((T) + 2 < 16)      asm volatile("s_waitcnt vmcnt(6)" ::: "memory");    \
            else if ((T) + 1 < 16) asm volatile("s_waitcnt vmcnt(0)" ::: "memory");    \
            __builtin_amdgcn_sched_barrier(0);                                         \
            __builtin_amdgcn_s_barrier();                                              \
            __builtin_amdgcn_sched_barrier(0);                                         \
            if ((T) + 1 < 16) readFrags(((T) + 1) % 3, ANXT, BNXT);                    \
            mfmaAll(ACUR, BCUR);                                                       \
        }

        #pragma unroll
        for (int tt = 0; tt < 16; tt += 2) {
            ITER_BODY(tt, aE, bE, aO, bO);
            ITER_BODY(tt + 1, aO, bO, aE, bE);
        }
        #undef ITER_BODY

        // epilogue (swapped layout): row = ...+fr, cols = ...+q*4+r -> one 8B store per (fm,fn)
        #pragma unroll
        for (int fm = 0; fm < 2; ++fm) {
            const int row = row0 + wr * 32 + fm * 16 + fr;
            #pragma unroll
            for (int fn = 0; fn < 4; ++fn) {
                const int c0 = col0 + wc * 64 + fn * 16 + q * 4;
                f32x4 bv = *reinterpret_cast<const f32x4*>(bias + c0);
                bf16x4 pk;
                #pragma unroll
                for (int r = 0; r < 4; ++r) pk[r] = (bf16)(acc[fm][fn][r] + bv[r]);
                store_u64_llc(&Z[(size_t)row * D_MODEL + c0], pk);
            }
        }
        signal_done(&zdone[bx]);
    }

    // ---------------- LN: out = LayerNorm(x + Z) * gamma + beta (wave-per-row, 8 rows/block)
    {
        const int w = tid >> 6, lane = tid & 63;
        const int r0 = (bid & 7) * 512 + (bid >> 3) * 8;
        wait_ge(&zdone[r0 >> 6], 8);               // my m-tile's 8 n-tile producers
        #pragma unroll
        for (int rr = 0; rr < 2; ++rr) {
            const int row = r0 + w * 2 + rr;
            const bf16* zr = Z + (size_t)row * D_MODEL;
            const float* xr = x + (size_t)row * D_MODEL;
            float z[4][4];
            float s = 0.0f, sq = 0.0f;
            #pragma unroll
            for (int c = 0; c < 4; ++c) {
                const int d = c * 256 + lane * 4;
                bf16x4 zv = *reinterpret_cast<const bf16x4*>(zr + d);
                f32x4 xv = *reinterpret_cast<const f32x4*>(xr + d);
                #pragma unroll
                for (int k = 0; k < 4; ++k) {
                    float v = xv[k] + (float)zv[k];
                    z[c][k] = v; s += v; sq += v * v;
                }
            }
            #pragma unroll
            for (int o = 1; o < 64; o <<= 1) { s += __shfl_xor(s, o, 64); sq += __shfl_xor(sq, o, 64); }
            const float mu = s * (1.0f / D_MODEL);
            const float var = sq * (1.0f / D_MODEL) - mu * mu;
            const float inv = rsqrtf(var + 1e-5f);
            float* outr = out + (size_t)row * D_MODEL;
            #pragma unroll
            for (int c = 0; c < 4; ++c) {
                const int d = c * 256 + lane * 4;
                f32x4 g = *reinterpret_cast<const f32x4*>(gamma + d);
                f32x4 be = *reinterpret_cast<const f32x4*>(beta + d);
                f32x4 o;
                #pragma unroll
                for (int k = 0; k < 4; ++k) o[k] = (z[c][k] - mu) * inv * g[k] + be[k];
                *reinterpret_cast<f32x4*>(outr + d) = o;
            }
        }
    }
}

extern "C" void kernel_launch(void* const* d_in, const int* in_sizes, int n_in,
                              void* d_out, int out_size, void* d_ws, size_t ws_size,
                              hipStream_t stream) {
    const float* x       = (const float*)d_in[0];
    const float* A_param = (const float*)d_in[1];
    const float* B_vec   = (const float*)d_in[2];
    const float* C_vec   = (const float*)d_in[3];
    const float* D_vec   = (const float*)d_in[4];
    const float* W       = (const float*)d_in[5];
    const float* b_proj  = (const float*)d_in[6];
    const float* gamma   = (const float*)d_in[7];
    const float* beta    = (const float*)d_in[8];
    float* out = (float*)d_out;

    char* ws = (char*)d_ws;
    float* partial = (float*)ws;                                  // 128 KiB
    bf16*  Wb      = (bf16*)(ws + (128 << 10));                   // 2 MiB
    bf16*  G       = (bf16*)(ws + (128 << 10) + (2 << 20));       // 8 MiB
    bf16*  Z       = (bf16*)(ws + (128 << 10) + (10 << 20));      // 8 MiB
    unsigned* sync = (unsigned*)(ws + (128 << 10) + (18 << 20));  // counters

    hipMemsetAsync(sync, 0, 1024, stream);
    hipLaunchKernelGGL(k_fused, dim3(512), dim3(256), 0, stream,
                       W, Wb, x, A_param, B_vec, C_vec, D_vec, partial,
                       G, Z, b_proj, gamma, beta, out, sync);
}

// Round 14
// 41.685 us; speedup vs baseline: 1.6511x; 1.6511x over previous
//
#include <hip/hip_runtime.h>
#include <hip/hip_bf16.h>
#include <math.h>

#define D_MODEL 1024
#define LSEQ 2048
#define BATCH 2
#define NROWS (BATCH*LSEQ)   // 4096
#define NACT 16              // active decay chunks
#define CHSL 16              // decay chunk length

typedef __bf16 bf16;
typedef __attribute__((ext_vector_type(8))) __bf16 bf16x8;
typedef __attribute__((ext_vector_type(4))) __bf16 bf16x4;
typedef __attribute__((ext_vector_type(4))) float f32x4;

__device__ __forceinline__ float sigA(float ap) {
    return fmaxf(1.0f / (1.0f + expf(-ap)), 1e-30f);
}

// async global->LDS, 16B/lane; LDS dest = wave-uniform base + lane*16
__device__ __forceinline__ void gload_lds16(const void* g, void* l) {
    __builtin_amdgcn_global_load_lds(
        (const __attribute__((address_space(1))) void*)g,
        (__attribute__((address_space(3))) void*)l, 16, 0, 0);
}

// ---------------- K1: decay partial sums (128 blocks)
__global__ __launch_bounds__(256) void k_decay(const float* __restrict__ x,
                                               const float* __restrict__ A_param,
                                               float* __restrict__ partial) {
    const int bid = blockIdx.x;                  // 0..127
    const int c = bid & 15, dg = (bid >> 4) & 3, b = bid >> 6;
    const int d = dg * 256 + threadIdx.x;
    const float A = sigA(A_param[d]);
    const float l2A = log2f(A);
    const int s0 = c * CHSL;
    float w = exp2f((float)s0 * l2A);
    float sum = 0.0f;
    const int jmax = (c == NACT - 1) ? (LSEQ - s0) : CHSL;  // last chunk extends (safety for large A)
    if (w != 0.0f) {
        const float* xp = x + ((size_t)b * LSEQ + s0) * D_MODEL + d;
        for (int j0 = 0; j0 < jmax; j0 += 8) {
            if (w == 0.0f) break;
            #pragma unroll
            for (int j = 0; j < 8; ++j) {
                sum += w * xp[(size_t)(j0 + j) * D_MODEL];
                w *= A;
            }
        }
    }
    partial[((size_t)b * NACT + c) * D_MODEL + d] = sum;
}

// ---------------- K2: prep (blocks 0..1023, XCD-aligned rows) + W cast (blocks 1024..1279)
// prep block bid writes G rows (bid&7)*512 + (bid>>3)*4 .. +4 -> panel (bid&7) stays in
// XCD (bid%8)'s L2, which is exactly where k_gemm's A-panel reader runs.
__global__ __launch_bounds__(256) void k_prep(const float* __restrict__ x,
                                              const float* __restrict__ A_param,
                                              const float* __restrict__ Bv,
                                              const float* __restrict__ Cv,
                                              const float* __restrict__ Dv,
                                              const float* __restrict__ partial,
                                              const float* __restrict__ W,
                                              bf16* __restrict__ Wb,
                                              bf16* __restrict__ G) {
    const int bid = blockIdx.x;
    const int tid = threadIdx.x;
    if (bid >= 1024) {                           // W f32 -> bf16 (256 blocks x 4 iters)
        const int base = bid - 1024;
        #pragma unroll
        for (int it = 0; it < 4; ++it) {
            const int idx = ((base * 256 + tid) + it * 65536) * 4;
            f32x4 v = *reinterpret_cast<const f32x4*>(W + idx);
            bf16x4 o;
            #pragma unroll
            for (int k = 0; k < 4; ++k) o[k] = (bf16)v[k];
            *reinterpret_cast<bf16x4*>(Wb + idx) = o;
        }
        return;
    }
    const int r0 = (bid & 7) * 512 + (bid >> 3) * 4;   // XCD-aligned 4-row chunk
    const int b = r0 >> 11;
    const int i0 = r0 & 2047;
    const int d0 = tid * 4;
    f32x4 P = {0.f, 0.f, 0.f, 0.f};
    #pragma unroll
    for (int c = 0; c < NACT; ++c)
        P += *reinterpret_cast<const f32x4*>(partial + ((size_t)b * NACT + c) * D_MODEL + d0);
    float A4[4], coeff[4], dvv[4], w[4];
    #pragma unroll
    for (int k = 0; k < 4; ++k) {
        A4[k] = sigA(A_param[d0 + k]);
        float l2 = log2f(A4[k]);
        coeff[k] = Cv[d0 + k] * Bv[d0 + k] * P[k];
        dvv[k] = Dv[d0 + k];
        w[k] = exp2f((float)(LSEQ - 1 - (i0 + 3)) * l2);   // conv(i) = coeff * A^(L-1-i)
    }
    #pragma unroll
    for (int j = 3; j >= 0; --j) {
        const int i = i0 + j;
        f32x4 xv = *reinterpret_cast<const f32x4*>(x + ((size_t)b * LSEQ + i) * D_MODEL + d0);
        bf16x4 g;
        #pragma unroll
        for (int k = 0; k < 4; ++k) {
            float u = coeff[k] * w[k] + dvv[k] * xv[k];
            g[k] = (bf16)(0.5f * u * (1.0f + erff(u * 0.70710678118654752f)));
            w[k] *= A4[k];
        }
        *reinterpret_cast<bf16x4*>(G + ((size_t)b * LSEQ + i) * D_MODEL + d0) = g;
    }
}

// ---------------- K3: Z = bf16(G @ Wb^T + bias)
// R7 pipeline (TM=64 TN=128 BK=64, 4 waves, 3 LDS buffers, reg-frag dbuf, 1 barrier/step,
// involutive row swizzle) + swapped-operand MFMA epilogue: lane holds one Z row and 4
// consecutive cols per fragment -> one 8B packed store (refcheck'd in R13).
__global__ __launch_bounds__(256) void k_gemm(const bf16* __restrict__ G,
                                              const bf16* __restrict__ Wb,
                                              const float* __restrict__ bias,
                                              bf16* __restrict__ Z) {
    __shared__ __align__(16) bf16 S[3 * 12288];   // 3 x 24KB = 72KB
    const int tid = threadIdx.x;
    const int lane = tid & 63, wave = tid >> 6;
    const int bid = blockIdx.x;
    const int bx = (bid & 7) * 8 + ((bid >> 3) & 7);   // m-tile: XCD-chunked
    const int by = bid >> 6;                           // n-tile [0,8)
    const int row0 = bx * 64, col0 = by * 128;
    const int wr = wave >> 1, wc = wave & 1;      // wave tile 32x64
    const int fr = lane & 15, q = lane >> 4;
    const int fx = fr & 7;
    f32x4 acc[2][4] = {};

    const int lr8 = lane >> 3;
    const int sb = 16 * ((lane & 7) ^ lr8);       // swizzled source byte-in-row
    const bf16* srcbase[6];
    #pragma unroll
    for (int r = 0; r < 6; ++r) {
        const int c = wave * 6 + r;
        const bf16* mat;
        int row;
        if (c < 8) { mat = G;  row = row0 + c * 8 + lr8; }
        else       { mat = Wb; row = col0 + (c - 8) * 8 + lr8; }
        srcbase[r] = (const bf16*)((const char*)(mat + (size_t)row * D_MODEL) + sb);
    }

    auto stage = [&](int buf, int k0) {
        #pragma unroll
        for (int r = 0; r < 6; ++r)
            gload_lds16(srcbase[r] + k0, &S[buf * 12288 + (wave * 6 + r) * 512]);
    };

    bf16x8 aE[2][2], bE[4][2], aO[2][2], bO[4][2];

    auto readFrags = [&](int bufI, bf16x8 (&a)[2][2], bf16x8 (&bb)[4][2]) {
        const bf16* SA = &S[bufI * 12288];
        const bf16* SB = SA + 4096;
        #pragma unroll
        for (int fm = 0; fm < 2; ++fm)
            #pragma unroll
            for (int ks = 0; ks < 2; ++ks)
                a[fm][ks] = *reinterpret_cast<const bf16x8*>(
                    SA + (wr * 32 + fm * 16 + fr) * 64 + 8 * ((4 * ks + q) ^ fx));
        #pragma unroll
        for (int fn = 0; fn < 4; ++fn)
            #pragma unroll
            for (int ks = 0; ks < 2; ++ks)
                bb[fn][ks] = *reinterpret_cast<const bf16x8*>(
                    SB + (wc * 64 + fn * 16 + fr) * 64 + 8 * ((4 * ks + q) ^ fx));
    };

    // swapped operands: D[i][j] = sum_k Wb[col+i][k] * G[row+j][k]
    // -> lane holds G-row j=fr and 4 consecutive cols i = q*4+r
    auto mfmaAll = [&](bf16x8 (&a)[2][2], bf16x8 (&bb)[4][2]) {
        __builtin_amdgcn_s_setprio(1);
        #pragma unroll
        for (int fm = 0; fm < 2; ++fm)
            #pragma unroll
            for (int fn = 0; fn < 4; ++fn)
                #pragma unroll
                for (int ks = 0; ks < 2; ++ks)
                    acc[fm][fn] = __builtin_amdgcn_mfma_f32_16x16x32_bf16(bb[fn][ks], a[fm][ks], acc[fm][fn], 0, 0, 0);
        __builtin_amdgcn_s_setprio(0);
    };

    stage(0, 0);
    stage(1, 64);
    asm volatile("s_waitcnt vmcnt(6)" ::: "memory");   // tile0 landed (tile1 in flight)
    __builtin_amdgcn_s_barrier();
    __builtin_amdgcn_sched_barrier(0);
    readFrags(0, aE, bE);

    #define ITER_BODY(T, ACUR, BCUR, ANXT, BNXT)                                   \
    {                                                                              \
        if ((T) + 2 < 16) stage(((T) + 2) % 3, ((T) + 2) * 64);                    \
        __builtin_amdgcn_sched_barrier(0);                                         \
        asm volatile("s_waitcnt lgkmcnt(0)" ::: "memory");                         \
        if ((T) + 2 < 16)      asm volatile("s_waitcnt vmcnt(6)" ::: "memory");    \
        else if ((T) + 1 < 16) asm volatile("s_waitcnt vmcnt(0)" ::: "memory");    \
        __builtin_amdgcn_sched_barrier(0);                                         \
        __builtin_amdgcn_s_barrier();                                              \
        __builtin_amdgcn_sched_barrier(0);                                         \
        if ((T) + 1 < 16) readFrags(((T) + 1) % 3, ANXT, BNXT);                    \
        mfmaAll(ACUR, BCUR);                                                       \
    }

    #pragma unroll
    for (int tt = 0; tt < 16; tt += 2) {
        ITER_BODY(tt, aE, bE, aO, bO);
        ITER_BODY(tt + 1, aO, bO, aE, bE);
    }
    #undef ITER_BODY

    // packed epilogue: one 8B store per (fm,fn)
    #pragma unroll
    for (int fm = 0; fm < 2; ++fm) {
        const int row = row0 + wr * 32 + fm * 16 + fr;
        #pragma unroll
        for (int fn = 0; fn < 4; ++fn) {
            const int c0 = col0 + wc * 64 + fn * 16 + q * 4;
            f32x4 bv = *reinterpret_cast<const f32x4*>(bias + c0);
            bf16x4 pk;
            #pragma unroll
            for (int r = 0; r < 4; ++r) pk[r] = (bf16)(acc[fm][fn][r] + bv[r]);
            *reinterpret_cast<bf16x4*>(&Z[(size_t)row * D_MODEL + c0]) = pk;
        }
    }
}

// ---------------- K4: out = LayerNorm(x + Z) * gamma + beta (wave-per-row, XCD-aligned)
__global__ __launch_bounds__(256) void k_ln(const bf16* __restrict__ Z,
                                            const float* __restrict__ x,
                                            const float* __restrict__ gamma,
                                            const float* __restrict__ beta,
                                            float* __restrict__ out) {
    const int w = threadIdx.x >> 6, lane = threadIdx.x & 63;
    const int row = (blockIdx.x & 7) * 512 + (blockIdx.x >> 3) * 4 + w;   // XCD-aligned
    const bf16* zr = Z + (size_t)row * D_MODEL;
    const float* xr = x + (size_t)row * D_MODEL;
    float z[4][4];
    float s = 0.0f, sq = 0.0f;
    #pragma unroll
    for (int c = 0; c < 4; ++c) {
        const int d = c * 256 + lane * 4;
        bf16x4 zv = *reinterpret_cast<const bf16x4*>(zr + d);
        f32x4 xv = *reinterpret_cast<const f32x4*>(xr + d);
        #pragma unroll
        for (int k = 0; k < 4; ++k) {
            float v = xv[k] + (float)zv[k];
            z[c][k] = v; s += v; sq += v * v;
        }
    }
    #pragma unroll
    for (int o = 1; o < 64; o <<= 1) { s += __shfl_xor(s, o, 64); sq += __shfl_xor(sq, o, 64); }
    const float mu = s * (1.0f / D_MODEL);
    const float var = sq * (1.0f / D_MODEL) - mu * mu;
    const float inv = rsqrtf(var + 1e-5f);
    float* outr = out + (size_t)row * D_MODEL;
    #pragma unroll
    for (int c = 0; c < 4; ++c) {
        const int d = c * 256 + lane * 4;
        f32x4 g = *reinterpret_cast<const f32x4*>(gamma + d);
        f32x4 be = *reinterpret_cast<const f32x4*>(beta + d);
        f32x4 o;
        #pragma unroll
        for (int k = 0; k < 4; ++k) o[k] = (z[c][k] - mu) * inv * g[k] + be[k];
        *reinterpret_cast<f32x4*>(outr + d) = o;
    }
}

extern "C" void kernel_launch(void* const* d_in, const int* in_sizes, int n_in,
                              void* d_out, int out_size, void* d_ws, size_t ws_size,
                              hipStream_t stream) {
    const float* x       = (const float*)d_in[0];
    const float* A_param = (const float*)d_in[1];
    const float* B_vec   = (const float*)d_in[2];
    const float* C_vec   = (const float*)d_in[3];
    const float* D_vec   = (const float*)d_in[4];
    const float* W       = (const float*)d_in[5];
    const float* b_proj  = (const float*)d_in[6];
    const float* gamma   = (const float*)d_in[7];
    const float* beta    = (const float*)d_in[8];
    float* out = (float*)d_out;

    char* ws = (char*)d_ws;
    float* partial = (float*)ws;                                  // 128 KiB
    bf16*  Wb      = (bf16*)(ws + (128 << 10));                   // 2 MiB
    bf16*  G       = (bf16*)(ws + (128 << 10) + (2 << 20));       // 8 MiB
    bf16*  Z       = (bf16*)(ws + (128 << 10) + (10 << 20));      // 8 MiB

    hipLaunchKernelGGL(k_decay, dim3(128), dim3(256), 0, stream, x, A_param, partial);
    hipLaunchKernelGGL(k_prep,  dim3(1280), dim3(256), 0, stream,
                       x, A_param, B_vec, C_vec, D_vec, partial, W, Wb, G);
    hipLaunchKernelGGL(k_gemm,  dim3(512), dim3(256), 0, stream, G, Wb, b_proj, Z);
    hipLaunchKernelGGL(k_ln,    dim3(1024), dim3(256), 0, stream, Z, x, gamma, beta, out);
}